// Round 1
// baseline (328.677 us; speedup 1.0000x reference)
//
#include <hip/hip_runtime.h>
#include <hip/hip_bf16.h>

typedef __bf16 bf16x8 __attribute__((ext_vector_type(8)));
typedef float floatx4 __attribute__((ext_vector_type(4)));

// ---- Cl(3) Cayley table, row i = first operand, col j = second. p = i*8+j ----
// basis: 0:1  1:e1  2:e2  3:e3  4:e12  5:e13  6:e23  7:e123
constexpr int TK[64] = {
  0,1,2,3,4,5,6,7,
  1,0,4,5,2,3,7,6,
  2,4,0,6,1,7,3,5,
  3,5,6,0,7,1,2,4,
  4,2,1,7,0,6,5,3,
  5,3,7,1,6,0,4,2,
  6,7,3,2,5,4,0,1,
  7,6,5,4,3,2,1,0
};
constexpr float SGN[64] = {
  1, 1, 1, 1, 1, 1, 1, 1,
  1, 1, 1, 1, 1, 1, 1, 1,
  1,-1, 1, 1,-1,-1, 1,-1,
  1,-1,-1, 1, 1,-1,-1, 1,
  1,-1, 1, 1,-1,-1, 1,-1,
  1,-1,-1, 1, 1,-1,-1, 1,
  1, 1,-1, 1,-1, 1,-1,-1,
  1, 1,-1, 1,-1, 1,-1,-1
};

__device__ __forceinline__ void async16(const void* g, void* l) {
  __builtin_amdgcn_global_load_lds(
      (const __attribute__((address_space(1))) void*)g,
      (__attribute__((address_space(3))) void*)l, 16, 0, 0);
}

// ---- Kernel A: cast+transpose weights to bf16 B^T layout (n-major, k contiguous) ----
__global__ __launch_bounds__(256) void conv_w(
    const float* __restrict__ Wg, const float* __restrict__ Wu, const float* __restrict__ Wd,
    __bf16* __restrict__ Bg, __bf16* __restrict__ Bu, __bf16* __restrict__ Bd)
{
  int idx = blockIdx.x * 256 + threadIdx.x;   // 0..262143
  {
    int n = idx >> 8, k = idx & 255;          // Bg/Bu: [1024][256]
    Bg[idx] = (__bf16)Wg[k * 1024 + n];
    Bu[idx] = (__bf16)Wu[k * 1024 + n];
  }
  {
    int n = idx >> 10, k = idx & 1023;        // Bd: [256][1024]
    Bd[idx] = (__bf16)Wd[k * 256 + n];
  }
}

// ---- Kernel B: geometric product + gate mix + LayerNorm -> bf16 flat [65536][256] ----
__global__ __launch_bounds__(256) void geo_ln(
    const float* __restrict__ X,   // [8192][8][256]
    const float* __restrict__ IW,  // [64]
    const float* __restrict__ GG,  // [1]
    const float* __restrict__ LW, const float* __restrict__ LB,
    __bf16* __restrict__ F)        // [65536][256]
{
  __shared__ float sw[64];
  __shared__ float smix[8 * 256];
  __shared__ float sstat[16];      // mu[0..7], rstd[8..15]
  const int t = threadIdx.x;
  const int tok = blockIdx.x;

  if (t < 64) sw[t] = SGN[t] / (1.f + __expf(-IW[t]));  // sg * sigmoid(iw)

  float xv[8];
  #pragma unroll
  for (int b = 0; b < 8; ++b) xv[b] = X[(size_t)tok * 2048 + b * 256 + t];
  const float g = 1.f / (1.f + __expf(-GG[0]));

  __syncthreads();

  float geo[8] = {0.f, 0.f, 0.f, 0.f, 0.f, 0.f, 0.f, 0.f};
  #pragma unroll
  for (int p = 0; p < 64; ++p)
    geo[TK[p]] += xv[p >> 3] * xv[p & 7] * sw[p];

  float mv[8];
  #pragma unroll
  for (int b = 0; b < 8; ++b) {
    mv[b] = g * geo[b] + (1.f - g) * xv[b];
    smix[b * 256 + t] = mv[b];
  }
  __syncthreads();

  // per-blade LN stats: wave wv reduces blades 2wv, 2wv+1 over 256 values
  const int wv = t >> 6, lane = t & 63;
  #pragma unroll
  for (int s = 0; s < 2; ++s) {
    int b = wv * 2 + s;
    float v0 = smix[b * 256 + lane];
    float v1 = smix[b * 256 + 64 + lane];
    float v2 = smix[b * 256 + 128 + lane];
    float v3 = smix[b * 256 + 192 + lane];
    float sum = v0 + v1 + v2 + v3;
    float sq  = v0*v0 + v1*v1 + v2*v2 + v3*v3;
    #pragma unroll
    for (int off = 32; off > 0; off >>= 1) {
      sum += __shfl_xor(sum, off, 64);
      sq  += __shfl_xor(sq,  off, 64);
    }
    if (lane == 0) {
      float mu  = sum * (1.f / 256.f);
      float var = sq * (1.f / 256.f) - mu * mu;
      sstat[b]     = mu;
      sstat[8 + b] = rsqrtf(var + 1e-5f);
    }
  }
  __syncthreads();

  const float lw = LW[t], lb = LB[t];
  #pragma unroll
  for (int b = 0; b < 8; ++b) {
    float v = (mv[b] - sstat[b]) * sstat[8 + b] * lw + lb;
    F[(size_t)(tok * 8 + b) * 256 + t] = (__bf16)v;
  }
}

// ---- Kernel C: fused gate+up GEMM + SwiGLU -> h bf16 [65536][1024] ----
// tile: 128 rows x 64 f-cols; computes both gate and up for the same cols.
__global__ __launch_bounds__(256) void gemm_gateup(
    const __bf16* __restrict__ A,   // flat [65536][256]
    const __bf16* __restrict__ Bg,  // [1024][256]
    const __bf16* __restrict__ Bu,  // [1024][256]
    __bf16* __restrict__ H)         // [65536][1024]
{
  __shared__ __bf16 sA[128 * 32];
  __shared__ __bf16 sBg[64 * 32];
  __shared__ __bf16 sBu[64 * 32];
  const int t = threadIdx.x;
  const int m0 = blockIdx.x * 128;
  const int f0 = blockIdx.y * 64;
  const int lane = t & 63, wv = t >> 6;
  const int wm = wv & 1, wf = wv >> 1;
  const int l15 = lane & 15, quad = lane >> 4;

  floatx4 zero = {0.f, 0.f, 0.f, 0.f};
  floatx4 accg[4][2], accu[4][2];
  #pragma unroll
  for (int im = 0; im < 4; ++im)
    #pragma unroll
    for (int jf = 0; jf < 2; ++jf) { accg[im][jf] = zero; accu[im][jf] = zero; }

  for (int k0 = 0; k0 < 256; k0 += 32) {
    #pragma unroll
    for (int i = 0; i < 2; ++i) {
      int idx = i * 256 + t;
      int row = idx >> 2, seg = idx & 3;
      async16(A + (size_t)(m0 + row) * 256 + k0 + seg * 8, &sA[idx * 8]);
    }
    {
      int row = t >> 2, seg = t & 3;
      async16(Bg + (size_t)(f0 + row) * 256 + k0 + seg * 8, &sBg[t * 8]);
      async16(Bu + (size_t)(f0 + row) * 256 + k0 + seg * 8, &sBu[t * 8]);
    }
    __syncthreads();

    bf16x8 af[4], bgf[2], buf[2];
    #pragma unroll
    for (int im = 0; im < 4; ++im)
      af[im] = *(const bf16x8*)&sA[(wm * 64 + im * 16 + l15) * 32 + quad * 8];
    #pragma unroll
    for (int jf = 0; jf < 2; ++jf) {
      bgf[jf] = *(const bf16x8*)&sBg[(wf * 32 + jf * 16 + l15) * 32 + quad * 8];
      buf[jf] = *(const bf16x8*)&sBu[(wf * 32 + jf * 16 + l15) * 32 + quad * 8];
    }
    #pragma unroll
    for (int im = 0; im < 4; ++im)
      #pragma unroll
      for (int jf = 0; jf < 2; ++jf) {
        accg[im][jf] = __builtin_amdgcn_mfma_f32_16x16x32_bf16(af[im], bgf[jf], accg[im][jf], 0, 0, 0);
        accu[im][jf] = __builtin_amdgcn_mfma_f32_16x16x32_bf16(af[im], buf[jf], accu[im][jf], 0, 0, 0);
      }
    __syncthreads();
  }

  #pragma unroll
  for (int im = 0; im < 4; ++im)
    #pragma unroll
    for (int jf = 0; jf < 2; ++jf)
      #pragma unroll
      for (int r = 0; r < 4; ++r) {
        int m = m0 + wm * 64 + im * 16 + quad * 4 + r;
        int f = f0 + wf * 32 + jf * 16 + l15;
        float gv = accg[im][jf][r];
        float uv = accu[im][jf][r];
        float hv = (gv / (1.f + __expf(-gv))) * uv;   // silu(g) * u
        H[(size_t)m * 1024 + f] = (__bf16)hv;
      }
}

// ---- Kernel D: down GEMM + residual. tile: 128 rows x 256 cols (full N, h read once) ----
__global__ __launch_bounds__(256) void gemm_down(
    const __bf16* __restrict__ A,   // h [65536][1024]
    const __bf16* __restrict__ B,   // Wd^T [256][1024]
    const float* __restrict__ X,    // residual [65536*256]
    float* __restrict__ O)          // [65536*256]
{
  __shared__ __bf16 sA[128 * 32];
  __shared__ __bf16 sB[256 * 32];
  const int t = threadIdx.x;
  const int m0 = blockIdx.x * 128;
  const int lane = t & 63, wv = t >> 6;
  const int wm = wv & 1, wn = wv >> 1;
  const int l15 = lane & 15, quad = lane >> 4;

  floatx4 zero = {0.f, 0.f, 0.f, 0.f};
  floatx4 acc[4][8];
  #pragma unroll
  for (int im = 0; im < 4; ++im)
    #pragma unroll
    for (int jn = 0; jn < 8; ++jn) acc[im][jn] = zero;

  for (int k0 = 0; k0 < 1024; k0 += 32) {
    #pragma unroll
    for (int i = 0; i < 2; ++i) {
      int idx = i * 256 + t, row = idx >> 2, seg = idx & 3;
      async16(A + (size_t)(m0 + row) * 1024 + k0 + seg * 8, &sA[idx * 8]);
    }
    #pragma unroll
    for (int i = 0; i < 4; ++i) {
      int idx = i * 256 + t, row = idx >> 2, seg = idx & 3;
      async16(B + (size_t)row * 1024 + k0 + seg * 8, &sB[idx * 8]);
    }
    __syncthreads();

    bf16x8 af[4], bfr[8];
    #pragma unroll
    for (int im = 0; im < 4; ++im)
      af[im] = *(const bf16x8*)&sA[(wm * 64 + im * 16 + l15) * 32 + quad * 8];
    #pragma unroll
    for (int jn = 0; jn < 8; ++jn)
      bfr[jn] = *(const bf16x8*)&sB[(wn * 128 + jn * 16 + l15) * 32 + quad * 8];
    #pragma unroll
    for (int im = 0; im < 4; ++im)
      #pragma unroll
      for (int jn = 0; jn < 8; ++jn)
        acc[im][jn] = __builtin_amdgcn_mfma_f32_16x16x32_bf16(af[im], bfr[jn], acc[im][jn], 0, 0, 0);
    __syncthreads();
  }

  #pragma unroll
  for (int im = 0; im < 4; ++im)
    #pragma unroll
    for (int jn = 0; jn < 8; ++jn)
      #pragma unroll
      for (int r = 0; r < 4; ++r) {
        int m = m0 + wm * 64 + im * 16 + quad * 4 + r;
        int n = wn * 128 + jn * 16 + l15;
        size_t o = (size_t)m * 256 + n;
        O[o] = X[o] + acc[im][jn][r];
      }
}

extern "C" void kernel_launch(void* const* d_in, const int* in_sizes, int n_in,
                              void* d_out, int out_size, void* d_ws, size_t ws_size,
                              hipStream_t stream) {
  const float* x   = (const float*)d_in[0];
  const float* iw  = (const float*)d_in[1];
  const float* gg  = (const float*)d_in[2];
  const float* lnw = (const float*)d_in[3];
  const float* lnb = (const float*)d_in[4];
  const float* Wg  = (const float*)d_in[5];
  const float* Wu  = (const float*)d_in[6];
  const float* Wd  = (const float*)d_in[7];
  float* out = (float*)d_out;

  char* ws = (char*)d_ws;
  __bf16* flat = (__bf16*)(ws);                      // 65536*256*2  = 32 MB
  __bf16* h    = (__bf16*)(ws + 33554432);           // 65536*1024*2 = 128 MB
  __bf16* Bg   = (__bf16*)(ws + 167772160);          // 512 KB
  __bf16* Bu   = (__bf16*)(ws + 168296448);          // 512 KB
  __bf16* Bd   = (__bf16*)(ws + 168820736);          // 512 KB

  conv_w<<<1024, 256, 0, stream>>>(Wg, Wu, Wd, Bg, Bu, Bd);
  geo_ln<<<8192, 256, 0, stream>>>(x, iw, gg, lnw, lnb, flat);
  gemm_gateup<<<dim3(512, 16), 256, 0, stream>>>(flat, Bg, Bu, h);
  gemm_down<<<512, 256, 0, stream>>>(h, Bd, x, out);
}